// Round 2
// baseline (526.076 us; speedup 1.0000x reference)
//
#include <hip/hip_runtime.h>
#include <hip/hip_bf16.h>
#include <stdint.h>

typedef unsigned short u16;
typedef unsigned int u32;

#define NV 400000
#define KOFF 27
#define EPS_BN 1e-5f

#define INV_ELEMS (KOFF * NV)            // 10.8M
#define INV_BYTES (INV_ELEMS * 4)        // 43.2 MB
#define FEATSBF_OFF INV_BYTES            // bf16 feats: 51.2 MB
#define WT_OFF (FEATSBF_OFF + NV * 64 * 2)
#define STATS_OFF (WT_OFF + KOFF * 64 * 64 * 2)

using short8 = __attribute__((ext_vector_type(8))) short;
using floatx4 = __attribute__((ext_vector_type(4))) float;

__device__ __forceinline__ u16 f2bf(float f) {
  u32 u = __float_as_uint(f);
  u += 0x7FFFu + ((u >> 16) & 1u);
  return (u16)(u >> 16);
}

// ---------------- init: inv = -1, stats = 0 ----------------
__global__ void k_init(int* __restrict__ inv, float* __restrict__ stats) {
  int i = blockIdx.x * 256 + threadIdx.x;
  if (i < INV_ELEMS / 4) ((int4*)inv)[i] = make_int4(-1, -1, -1, -1);
  if (blockIdx.x == 0) stats[threadIdx.x] = 0.0f;  // sum[64], sq[64], scale[64], shift[64]
}

// ---------------- convert feats fp32 -> bf16 ----------------
__global__ void k_cvt(const float* __restrict__ feats, u16* __restrict__ featsBf) {
  int i = blockIdx.x * 256 + threadIdx.x;   // one float4 per thread
  if (i >= NV * 64 / 4) return;
  float4 v = ((const float4*)feats)[i];
  ushort4 o;
  o.x = f2bf(v.x); o.y = f2bf(v.y); o.z = f2bf(v.z); o.w = f2bf(v.w);
  ((ushort4*)featsBf)[i] = o;
}

// ---------------- build inverse map: inv[k][out_idx] = in_idx ----------------
// within a fixed k, valid out_idx are distinct -> no write conflicts
__global__ void k_build(const int* __restrict__ in_idx, const int* __restrict__ out_idx,
                        const float* __restrict__ mask, int* __restrict__ inv) {
  int t = blockIdx.x * 256 + threadIdx.x;
  if (t >= INV_ELEMS) return;
  if (mask[t] != 0.0f) {
    int k = t / NV;
    inv[k * NV + out_idx[t]] = in_idx[t];
  }
}

// ---------------- transpose+convert W: Wt[k][o][c] = bf16(W[k][c][o]) ----------------
__global__ void k_wt(const float* __restrict__ W, u16* __restrict__ Wt) {
  int t = blockIdx.x * 256 + threadIdx.x;
  if (t >= KOFF * 64 * 64) return;
  int k = t >> 12, rem = t & 4095, c = rem >> 6, o = rem & 63;
  Wt[(k << 12) + (o << 6) + c] = f2bf(W[t]);
}

// ---------------- main: gather + MFMA GEMM + fused stats ----------------
__global__ void __launch_bounds__(256)
k_main(const u16* __restrict__ feats, const int* __restrict__ inv,
       const u16* __restrict__ Wt, float* __restrict__ out, float* __restrict__ stats) {
  __shared__ u16 Asm[64][72];   // 72-pitch: 2-way bank alias only (free)
  __shared__ u16 Wsm[64][72];   // Wt tile: [o][c]
  __shared__ int srcbuf[64];
  __shared__ float redS[4][64];
  __shared__ float redQ[4][64];

  const int t = threadIdx.x;
  const int lane = t & 63;
  const int wave = t >> 6;
  const int qm = lane & 15;
  const int quad = lane >> 4;
  const int j0 = blockIdx.x * 64;

  floatx4 acc[4];
#pragma unroll
  for (int nt = 0; nt < 4; ++nt) acc[nt] = (floatx4){0.f, 0.f, 0.f, 0.f};

  for (int k = 0; k < KOFF; ++k) {
    int src = -1;
    if (t < 64) { src = inv[k * NV + j0 + t]; srcbuf[t] = src; }
    int any = __syncthreads_or(src >= 0);  // barrier also protects LDS reuse across iters
    if (any) {
      // stage A: 64 rows x 128B; each thread two 16B chunks
      int r = t >> 3, seg = t & 7;
      int s0 = srcbuf[r];
      uint4 v0 = make_uint4(0, 0, 0, 0);
      if (s0 >= 0) v0 = *(const uint4*)(feats + s0 * 64 + seg * 8);
      *(uint4*)&Asm[r][seg * 8] = v0;
      int r2 = r + 32;
      int s1 = srcbuf[r2];
      uint4 v1 = make_uint4(0, 0, 0, 0);
      if (s1 >= 0) v1 = *(const uint4*)(feats + s1 * 64 + seg * 8);
      *(uint4*)&Asm[r2][seg * 8] = v1;
      // stage W^T tile: 8KB, coalesced
      const u16* wk = Wt + (k << 12);
      *(uint4*)&Wsm[t >> 3][(t & 7) * 8] = *(const uint4*)(wk + t * 8);
      int t2 = t + 256;
      *(uint4*)&Wsm[t2 >> 3][(t2 & 7) * 8] = *(const uint4*)(wk + t2 * 8);
    }
    __syncthreads();
    if (any) {
      // A frag: lane holds A[m=qm][k=quad*8+j]; wave w owns rows w*16..w*16+15
      const u16* ap = &Asm[wave * 16 + qm][quad * 8];
      short8 a0 = *(const short8*)ap;
      short8 a1 = *(const short8*)(ap + 32);
#pragma unroll
      for (int nt = 0; nt < 4; ++nt) {
        const u16* bp = &Wsm[nt * 16 + qm][quad * 8];
        short8 b0 = *(const short8*)bp;
        short8 b1 = *(const short8*)(bp + 32);
        acc[nt] = __builtin_amdgcn_mfma_f32_16x16x32_bf16(a0, b0, acc[nt], 0, 0, 0);
        acc[nt] = __builtin_amdgcn_mfma_f32_16x16x32_bf16(a1, b1, acc[nt], 0, 0, 0);
      }
    }
  }

  // epilogue: write pre-BN fp32; D layout: row = quad*4+reg, col = nt*16+qm
#pragma unroll
  for (int nt = 0; nt < 4; ++nt) {
#pragma unroll
    for (int r = 0; r < 4; ++r) {
      int row = j0 + wave * 16 + quad * 4 + r;
      out[row * 64 + nt * 16 + qm] = acc[nt][r];
    }
  }

  // fused channel stats: reduce within wave (rows live on quad axis), then block, then atomic
#pragma unroll
  for (int nt = 0; nt < 4; ++nt) {
    float s = acc[nt][0] + acc[nt][1] + acc[nt][2] + acc[nt][3];
    float q = acc[nt][0] * acc[nt][0] + acc[nt][1] * acc[nt][1] +
              acc[nt][2] * acc[nt][2] + acc[nt][3] * acc[nt][3];
    s += __shfl_xor(s, 16, 64); s += __shfl_xor(s, 32, 64);
    q += __shfl_xor(q, 16, 64); q += __shfl_xor(q, 32, 64);
    if (quad == 0) { redS[wave][nt * 16 + qm] = s; redQ[wave][nt * 16 + qm] = q; }
  }
  __syncthreads();
  if (t < 64) {
    float s = redS[0][t] + redS[1][t] + redS[2][t] + redS[3][t];
    float q = redQ[0][t] + redQ[1][t] + redQ[2][t] + redQ[3][t];
    atomicAdd(&stats[t], s);
    atomicAdd(&stats[64 + t], q);
  }
}

// ---------------- BN finalize: scale/shift ----------------
__global__ void k_stats(const float* __restrict__ stats, const float* __restrict__ gamma,
                        const float* __restrict__ beta, float* __restrict__ sc,
                        float* __restrict__ sh) {
  int t = threadIdx.x;
  float inv_n = 1.0f / (float)NV;
  float mean = stats[t] * inv_n;
  float var = stats[64 + t] * inv_n - mean * mean;
  float scale = gamma[t] * rsqrtf(var + EPS_BN);
  sc[t] = scale;
  sh[t] = beta[t] - mean * scale;
}

// ---------------- apply BN + ReLU in place (fp32) ----------------
__global__ void k_apply(float* __restrict__ out, const float* __restrict__ sc,
                        const float* __restrict__ sh) {
  int i = blockIdx.x * 256 + threadIdx.x;   // one float4 per thread
  if (i >= NV * 64 / 4) return;
  int c0 = (i & 15) * 4;
  float4 v = ((const float4*)out)[i];
  float* pv = (float*)&v;
#pragma unroll
  for (int j = 0; j < 4; ++j) {
    float y = pv[j] * sc[c0 + j] + sh[c0 + j];
    pv[j] = y > 0.f ? y : 0.f;
  }
  ((float4*)out)[i] = v;
}

extern "C" void kernel_launch(void* const* d_in, const int* in_sizes, int n_in,
                              void* d_out, int out_size, void* d_ws, size_t ws_size,
                              hipStream_t stream) {
  const float* feats = (const float*)d_in[0];
  const float* W     = (const float*)d_in[1];
  const float* gamma = (const float*)d_in[2];
  const float* beta  = (const float*)d_in[3];
  const float* mask  = (const float*)d_in[4];
  const int* in_idx  = (const int*)d_in[5];
  const int* out_idx = (const int*)d_in[6];
  float* out = (float*)d_out;

  char* ws = (char*)d_ws;
  int* inv = (int*)ws;                        // 43.2 MB
  u16* featsBf = (u16*)(ws + FEATSBF_OFF);    // 51.2 MB
  u16* Wt = (u16*)(ws + WT_OFF);              // 216 KB
  float* stats = (float*)(ws + STATS_OFF);    // 256 floats

  k_init<<<(INV_ELEMS / 4 + 255) / 256, 256, 0, stream>>>(inv, stats);
  k_cvt<<<(NV * 64 / 4 + 255) / 256, 256, 0, stream>>>(feats, featsBf);
  k_build<<<(INV_ELEMS + 255) / 256, 256, 0, stream>>>(in_idx, out_idx, mask, inv);
  k_wt<<<(KOFF * 4096 + 255) / 256, 256, 0, stream>>>(W, Wt);
  k_main<<<NV / 64, 256, 0, stream>>>(featsBf, inv, Wt, out, stats);
  k_stats<<<1, 64, 0, stream>>>(stats, gamma, beta, stats + 128, stats + 192);
  k_apply<<<(NV * 64 / 4 + 255) / 256, 256, 0, stream>>>(out, stats + 128, stats + 192);
}